// Round 8
// baseline (171.301 us; speedup 1.0000x reference)
//
#include <hip/hip_runtime.h>

// NestedConv via MFMA bf16: B=64, N=128, D=64.
// out[b,i,j,:] = m[b,i,j] * sum_k A[b,k,j] * h[b,i,k,:]
// h = relu(relu((m*X)@W1+b1)@W2+b2),  A symmetric 0/1 (bf16-exact).
//
// Round-8 = Round-3 skeleton (best, 133us) + :
//  - IPB=2 tiles/block; tile-1 X loads issued during tile-0 compute (T14).
//  - barrier minimization: Sa (Xs/H1) is wave-private by construction ->
//    only H2T (Sbuf) needs barriers. 3 barriers/block vs 10.
//  - zero-row skip: device flag = (b1==0 && b2==0); if set, masked-off rows'
//    X loads are predicated off (h-row provably 0). Halves X fetch.
//  - cvtpk packing in hot paths.
#define Bv 64
#define Nv 128
#define Dv 64

// ws layout (bytes): [0,16K) wpk; [20480] flag; [32K, 32K+2M) apk.
#define FLAG_OFF_B 20480
#define APK_OFF_B  32768
#define WS_NEED (32768 + Bv * 32768)

typedef __attribute__((ext_vector_type(8))) short bf16x8;
typedef __attribute__((ext_vector_type(4))) float f32x4;
typedef __attribute__((ext_vector_type(4))) unsigned u32x4;

__device__ __forceinline__ unsigned short f2bf(float f) {
    unsigned u = __float_as_uint(f);
    u += 0x7FFFu + ((u >> 16) & 1u);
    return (unsigned short)(u >> 16);
}
__device__ __forceinline__ unsigned cvtpk(float lo, float hi) {
    unsigned r;
    asm("v_cvt_pk_bf16_f32 %0, %1, %2" : "=v"(r) : "v"(lo), "v"(hi));
    return r;
}
__device__ __forceinline__ bf16x8 pack8m(float4 a, float4 b, float m) {
    u32x4 pk;
    pk[0] = cvtpk(m * a.x, m * a.y);
    pk[1] = cvtpk(m * a.z, m * a.w);
    pk[2] = cvtpk(m * b.x, m * b.y);
    pk[3] = cvtpk(m * b.z, m * b.w);
    return __builtin_bit_cast(bf16x8, pk);
}
__device__ __forceinline__ bf16x8 pack8(float4 a, float4 b) {
    bf16x8 r;
    r[0] = (short)f2bf(a.x); r[1] = (short)f2bf(a.y);
    r[2] = (short)f2bf(a.z); r[3] = (short)f2bf(a.w);
    r[4] = (short)f2bf(b.x); r[5] = (short)f2bf(b.y);
    r[6] = (short)f2bf(b.z); r[7] = (short)f2bf(b.w);
    return r;
}
__device__ __forceinline__ uint2 relu_pk4(f32x4 v) {
    return make_uint2(cvtpk(fmaxf(v[0], 0.f), fmaxf(v[1], 0.f)),
                      cvtpk(fmaxf(v[2], 0.f), fmaxf(v[3], 0.f)));
}
__device__ __forceinline__ int swz128(int r, int bi) {
    return r * 128 + (((bi & ~15) ^ ((r & 7) << 4)) | (bi & 15));
}
// fallback W fragment loader (PRE=false only)
__device__ __forceinline__ bf16x8 load_w_frag(const float* __restrict__ W,
                                              int kkbase, int dn, int l15, int l16) {
    const float* p = W + (kkbase + 8 * l16) * Dv + dn + l15;
    bf16x8 r;
    #pragma unroll
    for (int t = 0; t < 8; ++t) r[t] = (short)f2bf(p[t * Dv]);
    return r;
}

// ---- pre-kernel: pack W1,W2 fragments (16x16x32 B-operand order) ----
__global__ void pack_w_kernel(const float* __restrict__ W1,
                              const float* __restrict__ W2,
                              unsigned short* __restrict__ wpk) {
    const int idx = blockIdx.x * 256 + threadIdx.x;   // 1024 items
    const int l = idx & 63, f = idx >> 6;             // f = 0..15
    const int layer = f >> 3, kk = (f >> 2) & 1, tn = f & 3;
    const float* W = layer ? W2 : W1;
    const float* p = W + (kk * 32 + 8 * (l >> 4)) * Dv + tn * 16 + (l & 15);
    unsigned short* o = wpk + f * 512 + l * 8;
    #pragma unroll
    for (int t = 0; t < 8; ++t) o[t] = f2bf(p[t * Dv]);
}

// ---- pre-kernel: pack A fragments (A-operand rows j; A symmetric) ----
// Apk[b][jt][kk][l][t] = A[b][jt*16+(l&15)][kk*32+8*(l>>4)+t]
__global__ void pack_a_kernel(const float* __restrict__ A,
                              unsigned short* __restrict__ apk) {
    const int gid = blockIdx.x * 256 + threadIdx.x;   // 131072 items
    const int l = gid & 63, f = gid >> 6;             // f = b*32 + jt*4 + kk
    const int b = f >> 5, r = f & 31, jt = r >> 2, kk = r & 3;
    const float4* p = (const float4*)(A +
        ((size_t)(b * Nv + jt * 16 + (l & 15))) * Nv + kk * 32 + 8 * (l >> 4));
    *(bf16x8*)(apk + (size_t)f * 512 + l * 8) = pack8(p[0], p[1]);
}

// ---- pre-kernel: flag = 1 iff all biases are exactly zero ----
__global__ void check_bias(const float* __restrict__ b1,
                           const float* __restrict__ b2,
                           int* __restrict__ flag) {
    __shared__ int nz;
    if (threadIdx.x == 0) nz = 0;
    __syncthreads();
    const float v = (threadIdx.x < 64) ? b1[threadIdx.x] : b2[threadIdx.x - 64];
    if (v != 0.0f) atomicOr(&nz, 1);
    __syncthreads();
    if (threadIdx.x == 0) flag[0] = (nz == 0) ? 1 : 0;
}

template <bool PRE>
__global__ __launch_bounds__(256, 3)
void nested_conv_mfma(const float* __restrict__ X,
                      const float* __restrict__ A,
                      const int*   __restrict__ mask,
                      const float* __restrict__ W1,
                      const float* __restrict__ b1,
                      const float* __restrict__ W2,
                      const float* __restrict__ b2,
                      const unsigned short* __restrict__ wpk,
                      const unsigned short* __restrict__ apk,
                      const int*   __restrict__ bzflag,
                      float* __restrict__ out)
{
    __shared__ __align__(16) unsigned char Sa[16384];   // Xs then H1 (wave-private rows)
    __shared__ __align__(16) unsigned char Sbuf[16384]; // H2T (cross-wave)

    const int bx = blockIdx.x, b = blockIdx.y;
    const int tid = threadIdx.x;
    const int l = tid & 63, w = tid >> 6, l15 = l & 15, l16 = l >> 4;
    const int i0 = bx * 2;
    const int flz = PRE ? bzflag[0] : 0;   // 1 => biases zero => masked rows skippable

    // stage mapping: lane handles row sr (wave band [32w,32w+32)), half sh
    const int sr = tid >> 1;
    const int sh = (tid & 1) << 5;

    // hoisted biases
    float b1v[4], b2v[4];
    #pragma unroll
    for (int tn = 0; tn < 4; ++tn) { b1v[tn] = b1[tn * 16 + l15]; b2v[tn] = b2[tn * 16 + l15]; }

    const unsigned short* Apb = PRE ? apk + (size_t)b * 32 * 512 : nullptr;
    const float*          Ab  = A + (size_t)b * Nv * Nv;

    // ---- X/mask loads for a tile into registers (predicated by zero-skip) ----
#define LOADX(I, XV, SM) do {                                                     \
        const size_t bi_ = (size_t)(b * Nv + (I));                                \
        SM = mask[bi_ * Nv + sr] ? 1.0f : 0.0f;                                   \
        const float4* xp_ = (const float4*)(X + (bi_ * Nv + sr) * Dv + sh);       \
        if (!flz || SM != 0.0f) {                                                 \
            _Pragma("unroll")                                                     \
            for (int g_ = 0; g_ < 8; ++g_) XV[g_] = xp_[g_];                      \
        } else {                                                                  \
            _Pragma("unroll")                                                     \
            for (int g_ = 0; g_ < 8; ++g_) XV[g_] = make_float4(0.f,0.f,0.f,0.f); \
        }                                                                         \
    } while (0)

    float4 xv0[8], xv1[8];
    float  sm0, sm1;
    LOADX(i0, xv0, sm0);   // tile-0 X: issued first thing

#define DO_TILE(T, XV, SM, PREFETCH, TRAILBAR)                                    \
    {                                                                             \
        const int i = i0 + (T);                                                   \
        const size_t bi = (size_t)(b * Nv + i);                                   \
        /* ---- stage: write masked bf16 Xs[r][d] into Sa (swizzled) ---- */      \
        _Pragma("unroll")                                                         \
        for (int g = 0; g < 4; ++g)                                               \
            *(bf16x8*)&Sa[swz128(sr, 2 * sh + 16 * g)] =                          \
                pack8m(XV[2 * g], XV[2 * g + 1], SM);                             \
        PREFETCH;   /* issue next tile's X loads: hidden under L1/L2 below */     \
        /* ---- L1: H1 = relu(Xs @ W1 + b1)  (all wave-private) ---- */           \
        f32x4 acc[2][4];                                                          \
        _Pragma("unroll")                                                         \
        for (int tn = 0; tn < 4; ++tn) {                                          \
            acc[0][tn] = (f32x4){b1v[tn], b1v[tn], b1v[tn], b1v[tn]};             \
            acc[1][tn] = acc[0][tn];                                              \
        }                                                                         \
        _Pragma("unroll")                                                         \
        for (int kk = 0; kk < 2; ++kk) {                                          \
            bf16x8 af[2];                                                         \
            _Pragma("unroll")                                                     \
            for (int mm = 0; mm < 2; ++mm) {                                      \
                const int r = (2 * w + mm) * 16 + l15;                            \
                af[mm] = *(const bf16x8*)&Sa[r * 128 +                            \
                              ((kk * 64 + 16 * l16) ^ ((l15 & 7) << 4))];         \
            }                                                                     \
            _Pragma("unroll")                                                     \
            for (int tn = 0; tn < 4; ++tn) {                                      \
                const bf16x8 wf = PRE                                             \
                    ? *(const bf16x8*)(wpk + (kk * 4 + tn) * 512 + l * 8)         \
                    : load_w_frag(W1, kk * 32, tn * 16, l15, l16);                \
                acc[0][tn] = __builtin_amdgcn_mfma_f32_16x16x32_bf16(af[0], wf, acc[0][tn], 0, 0, 0); \
                acc[1][tn] = __builtin_amdgcn_mfma_f32_16x16x32_bf16(af[1], wf, acc[1][tn], 0, 0, 0); \
            }                                                                     \
        }                                                                         \
        /* H1[r][d] scalar writes (wave-private rows) */                          \
        _Pragma("unroll")                                                         \
        for (int mm = 0; mm < 2; ++mm)                                            \
            _Pragma("unroll")                                                     \
            for (int tn = 0; tn < 4; ++tn)                                        \
                _Pragma("unroll")                                                 \
                for (int rg = 0; rg < 4; ++rg) {                                  \
                    const int r = (2 * w + mm) * 16 + 4 * l16 + rg;               \
                    const int d = tn * 16 + l15;                                  \
                    *(unsigned short*)&Sa[swz128(r, 2 * d)] =                     \
                        f2bf(fmaxf(acc[mm][tn][rg], 0.0f));                       \
                }                                                                 \
        /* ---- L2: H2 = relu(H1 @ W2 + b2) (wave-private reads) ---- */          \
        _Pragma("unroll")                                                         \
        for (int tn = 0; tn < 4; ++tn) {                                          \
            acc[0][tn] = (f32x4){b2v[tn], b2v[tn], b2v[tn], b2v[tn]};             \
            acc[1][tn] = acc[0][tn];                                              \
        }                                                                         \
        _Pragma("unroll")                                                         \
        for (int kk = 0; kk < 2; ++kk) {                                          \
            bf16x8 af[2];                                                         \
            _Pragma("unroll")                                                     \
            for (int mm = 0; mm < 2; ++mm) {                                      \
                const int r = (2 * w + mm) * 16 + l15;                            \
                af[mm] = *(const bf16x8*)&Sa[r * 128 +                            \
                              ((kk * 64 + 16 * l16) ^ ((l15 & 7) << 4))];         \
            }                                                                     \
            _Pragma("unroll")                                                     \
            for (int tn = 0; tn < 4; ++tn) {                                      \
                const bf16x8 wf = PRE                                             \
                    ? *(const bf16x8*)(wpk + (8 + kk * 4 + tn) * 512 + l * 8)     \
                    : load_w_frag(W2, kk * 32, tn * 16, l15, l16);                \
                acc[0][tn] = __builtin_amdgcn_mfma_f32_16x16x32_bf16(af[0], wf, acc[0][tn], 0, 0, 0); \
                acc[1][tn] = __builtin_amdgcn_mfma_f32_16x16x32_bf16(af[1], wf, acc[1][tn], 0, 0, 0); \
            }                                                                     \
        }                                                                         \
        /* H2T[d][k] vector writes into Sbuf (cross-wave consumer) */             \
        _Pragma("unroll")                                                         \
        for (int mm = 0; mm < 2; ++mm)                                            \
            _Pragma("unroll")                                                     \
            for (int tn = 0; tn < 4; ++tn) {                                      \
                const int d  = tn * 16 + l15;                                     \
                const int kb = (2 * w + mm) * 16 + 4 * l16;                       \
                const int inrow = 2 * kb;                                         \
                const int addr  = d * 256 +                                       \
                    (((inrow & ~15) ^ ((d & 7) << 4)) | (inrow & 15));            \
                *(uint2*)&Sbuf[addr] = relu_pk4(acc[mm][tn]);                     \
            }                                                                     \
        __syncthreads();   /* H2T complete */                                     \
        /* ---- P2: out[j][d] = sum_k A[b,j,k] * H2[k][d] ---- */                 \
        f32x4 acc2[2][4];                                                         \
        _Pragma("unroll")                                                         \
        for (int jj = 0; jj < 2; ++jj)                                            \
            _Pragma("unroll")                                                     \
            for (int td = 0; td < 4; ++td)                                        \
                acc2[jj][td] = (f32x4){0.f, 0.f, 0.f, 0.f};                       \
        _Pragma("unroll")                                                         \
        for (int kk = 0; kk < 4; ++kk) {                                          \
            bf16x8 anf[2];                                                        \
            _Pragma("unroll")                                                     \
            for (int jj = 0; jj < 2; ++jj) {                                      \
                const int jt = 2 * w + jj;                                        \
                if (PRE) {                                                        \
                    anf[jj] = *(const bf16x8*)(Apb + (jt * 4 + kk) * 512 + l * 8);\
                } else {                                                          \
                    const float4* ap = (const float4*)(Ab +                       \
                        (size_t)(jt * 16 + l15) * Nv + kk * 32 + 8 * l16);        \
                    anf[jj] = pack8(ap[0], ap[1]);                                \
                }                                                                 \
            }                                                                     \
            _Pragma("unroll")                                                     \
            for (int td = 0; td < 4; ++td) {                                      \
                const int d = td * 16 + l15;                                      \
                const bf16x8 bfr = *(const bf16x8*)&Sbuf[d * 256 +                \
                              ((kk * 64 + 16 * l16) ^ ((l15 & 7) << 4))];         \
                acc2[0][td] = __builtin_amdgcn_mfma_f32_16x16x32_bf16(anf[0], bfr, acc2[0][td], 0, 0, 0); \
                acc2[1][td] = __builtin_amdgcn_mfma_f32_16x16x32_bf16(anf[1], bfr, acc2[1][td], 0, 0, 0); \
            }                                                                     \
        }                                                                         \
        TRAILBAR;   /* Sbuf reads retired before next tile's H2T writes */        \
        /* ---- masked store ---- */                                              \
        const int*  mrow  = mask + bi * Nv;                                       \
        float*      Obase = out + bi * Nv * Dv;                                   \
        _Pragma("unroll")                                                         \
        for (int jj = 0; jj < 2; ++jj)                                            \
            _Pragma("unroll")                                                     \
            for (int rg = 0; rg < 4; ++rg) {                                      \
                const int j = (2 * w + jj) * 16 + 4 * l16 + rg;                   \
                const float msk = mrow[j] ? 1.0f : 0.0f;                          \
                float* orow = Obase + (size_t)j * Dv + l15;                       \
                _Pragma("unroll")                                                 \
                for (int td = 0; td < 4; ++td)                                    \
                    orow[td * 16] = acc2[jj][td][rg] * msk;                       \
            }                                                                     \
    }

    DO_TILE(0, xv0, sm0, LOADX(i0 + 1, xv1, sm1), __syncthreads());
    DO_TILE(1, xv1, sm1, (void)0, (void)0);

#undef DO_TILE
#undef LOADX
}

extern "C" void kernel_launch(void* const* d_in, const int* in_sizes, int n_in,
                              void* d_out, int out_size, void* d_ws, size_t ws_size,
                              hipStream_t stream) {
    const float* X    = (const float*)d_in[0];
    const float* A    = (const float*)d_in[1];
    const int*   mask = (const int*)d_in[2];
    const float* W1   = (const float*)d_in[3];
    const float* b1   = (const float*)d_in[4];
    const float* W2   = (const float*)d_in[5];
    const float* b2   = (const float*)d_in[6];
    float* out = (float*)d_out;

    dim3 grid(Nv / 2, Bv);   // blocks sharing b adjacent -> A[b]/apk[b] L2-hot

    if (ws_size >= (size_t)WS_NEED) {
        unsigned char* ws = (unsigned char*)d_ws;
        unsigned short* wpk  = (unsigned short*)ws;
        int*            flag = (int*)(ws + FLAG_OFF_B);
        unsigned short* apk  = (unsigned short*)(ws + APK_OFF_B);
        pack_w_kernel<<<4, 256, 0, stream>>>(W1, W2, wpk);
        pack_a_kernel<<<512, 256, 0, stream>>>(A, apk);
        check_bias<<<1, 128, 0, stream>>>(b1, b2, flag);
        nested_conv_mfma<true><<<grid, 256, 0, stream>>>(
            X, A, mask, W1, b1, W2, b2, wpk, apk, flag, out);
    } else {
        nested_conv_mfma<false><<<grid, 256, 0, stream>>>(
            X, A, mask, W1, b1, W2, b2, nullptr, nullptr, nullptr, out);
    }
}

// Round 9
// 165.441 us; speedup vs baseline: 1.0354x; 1.0354x over previous
//
#include <hip/hip_runtime.h>

// NestedConv via MFMA bf16: B=64, N=128, D=64.
// out[b,i,j,:] = m[b,i,j] * sum_k A[b,k,j] * h[b,i,k,:]
// h = relu(relu((m*X)@W1+b1)@W2+b2),  A symmetric 0/1 (bf16-exact).
//
// Round-9: R3 skeleton re-engineered for TOTAL regs <= 64 (VGPR+acc, unified
// file) -> 8 waves/SIMD instead of 4 (m69 cliff at 64). One 16 KB LDS buffer,
// 3 barriers, 32x32x16 MFMA with register-only L1->L2 handoff (permlane32_swap,
// layout verified in R7), one f32x16 accumulator live at a time (phases split
// over dt2 / nt / dts).
#define Bv 64
#define Nv 128
#define Dv 64

#define APK_OFF_B 32768
#define WS_NEED (32768 + Bv * 32768)

typedef __attribute__((ext_vector_type(8)))  short    bf16x8;
typedef __attribute__((ext_vector_type(16))) float    f32x16;
typedef __attribute__((ext_vector_type(4)))  unsigned u32x4;

__device__ __forceinline__ unsigned short f2bf(float f) {
    unsigned u = __float_as_uint(f);
    u += 0x7FFFu + ((u >> 16) & 1u);
    return (unsigned short)(u >> 16);
}
__device__ __forceinline__ unsigned cvtpk(float lo, float hi) {
    unsigned r;
    asm("v_cvt_pk_bf16_f32 %0, %1, %2" : "=v"(r) : "v"(lo), "v"(hi));
    return r;
}
// exchange: d' = {d.lo32, s.lo32}, s' = {d.hi32, s.hi32} (lane halves)
__device__ __forceinline__ void plswap(unsigned &d, unsigned &s) {
    asm("v_permlane32_swap_b32 %0, %1" : "+v"(d), "+v"(s));
}
__device__ __forceinline__ bf16x8 pack8m(float4 a, float4 b, float m) {
    u32x4 pk;
    pk[0] = cvtpk(m * a.x, m * a.y);
    pk[1] = cvtpk(m * a.z, m * a.w);
    pk[2] = cvtpk(m * b.x, m * b.y);
    pk[3] = cvtpk(m * b.z, m * b.w);
    return __builtin_bit_cast(bf16x8, pk);
}
__device__ __forceinline__ bf16x8 pack8f(float4 a, float4 b) {
    bf16x8 r;
    r[0] = (short)f2bf(a.x); r[1] = (short)f2bf(a.y);
    r[2] = (short)f2bf(a.z); r[3] = (short)f2bf(a.w);
    r[4] = (short)f2bf(b.x); r[5] = (short)f2bf(b.y);
    r[6] = (short)f2bf(b.z); r[7] = (short)f2bf(b.w);
    return r;
}
__device__ __forceinline__ bf16x8 frag_from(uint2 lo, uint2 hi) {
    u32x4 u = {lo.x, lo.y, hi.x, hi.y};
    return __builtin_bit_cast(bf16x8, u);
}
// relu + pack C-reg block q (4 consecutive rows) -> 8 B
__device__ __forceinline__ uint2 rpk(const f32x16 a, int q) {
    return make_uint2(cvtpk(fmaxf(a[4*q+0], 0.f), fmaxf(a[4*q+1], 0.f)),
                      cvtpk(fmaxf(a[4*q+2], 0.f), fmaxf(a[4*q+3], 0.f)));
}
__device__ __forceinline__ int swz128(int r, int bo) {
    return r * 128 + (((bo & ~15) ^ ((r & 7) << 4)) | (bo & 15));
}
__device__ __forceinline__ bf16x8 frag_strided(const float* p, int stride) {
    bf16x8 r;
    #pragma unroll
    for (int t = 0; t < 8; ++t) r[t] = (short)f2bf(p[t * stride]);
    return r;
}

// ---- pre-kernel: pack W1,W2 into 32x32-fragment order (R7-verified) ----
// wpk[f][l][t], f = layer*8 + half*4 + kt: value = W[kt*16+8*(l>>5)+t][half*32+(l&31)]
__global__ void pack_w32(const float* __restrict__ W1,
                         const float* __restrict__ W2,
                         unsigned short* __restrict__ wpk) {
    const int idx = blockIdx.x * 256 + threadIdx.x;   // 1024
    const int l = idx & 63, f = idx >> 6;
    const int layer = f >> 3, half = (f >> 2) & 1, kt = f & 3;
    const float* W = layer ? W2 : W1;
    const float* p = W + (kt * 16 + 8 * (l >> 5)) * Dv + half * 32 + (l & 31);
    unsigned short* o = wpk + f * 512 + l * 8;
    #pragma unroll
    for (int t = 0; t < 8; ++t) o[t] = f2bf(p[t * Dv]);
}

// ---- pre-kernel: pack A into 32x32 B-fragment order (R7-verified) ----
// apk[b][jt][kts][l][t] = A[b][j = jt*32+(l&31)][k = kts*16+8*(l>>5)+t]
__global__ void pack_a32(const float* __restrict__ A,
                         unsigned short* __restrict__ apk) {
    const int gid = blockIdx.x * 256 + threadIdx.x;   // 131072
    const int l = gid & 63, f = gid >> 6;             // f = b*32 + jt*8 + kts
    const int b = f >> 5, r = f & 31, jt = r >> 3, kts = r & 7;
    const float4* p = (const float4*)(A + ((size_t)b * Nv + jt * 32 + (l & 31)) * Nv
                                        + kts * 16 + 8 * (l >> 5));
    *(bf16x8*)(apk + (size_t)f * 512 + l * 8) = pack8f(p[0], p[1]);
}

template <bool PRE>
__global__ __launch_bounds__(256, 8)
void nested_conv_hyb(const float* __restrict__ X,
                     const float* __restrict__ A,
                     const int*   __restrict__ mask,
                     const float* __restrict__ W1,
                     const float* __restrict__ b1,
                     const float* __restrict__ W2,
                     const float* __restrict__ b2,
                     const unsigned short* __restrict__ wpk,
                     const unsigned short* __restrict__ apk,
                     float* __restrict__ out)
{
    // ONE 16 KB buffer: Xs[128 r][64 d] bf16 swizzled, then H2T[64 d][128 k].
    __shared__ __align__(16) unsigned char Sb[16384];

    const int tid = threadIdx.x;
    const int l = tid & 63, w = tid >> 6;
    const int l31 = l & 31, g = l >> 5;
    const int i = blockIdx.x, b = blockIdx.y;
    const size_t bi = (size_t)(b * Nv + i);

    // ---- stage masked X as bf16 (coalesced: 2 lanes per 256-B row) ----
    {
        const int sr = tid >> 1;
        const int sh = (tid & 1) << 5;
        const float mm = mask[bi * Nv + sr] ? 1.0f : 0.0f;
        const float4* xp = (const float4*)(X + (bi * Nv + sr) * Dv + sh);
        #pragma unroll
        for (int c = 0; c < 4; ++c)
            *(bf16x8*)&Sb[swz128(sr, 2 * sh + 16 * c)] = pack8m(xp[2*c], xp[2*c+1], mm);
    }
    __syncthreads();   // barrier #1: Xs ready

    const int r = 32 * w + l31;     // this lane's Xs row (wave-banded)

    // ===== L1 (swapped, 32x32x16): H1T-tile = W1^T @ Xm^T, one dt2 half at a time =====
    uint2 R1[2][4];   // packed H1 rows: [dt2][q]
    #pragma unroll
    for (int dt2 = 0; dt2 < 2; ++dt2) {
        f32x16 a1;
        #pragma unroll
        for (int q = 0; q < 4; ++q) {   // init = b1[d], d = dt2*32 + 8q + 4g + e
            const float4 bv = *(const float4*)&b1[dt2 * 32 + q * 8 + g * 4];
            a1[4*q+0] = bv.x; a1[4*q+1] = bv.y; a1[4*q+2] = bv.z; a1[4*q+3] = bv.w;
        }
        #pragma unroll
        for (int kt = 0; kt < 4; ++kt) {
            const bf16x8 xf = *(const bf16x8*)&Sb[swz128(r, kt * 32 + 16 * g)];
            const bf16x8 wf = PRE
                ? *(const bf16x8*)(wpk + (size_t)(dt2 * 4 + kt) * 512 + l * 8)
                : frag_strided(W1 + (kt * 16 + 8 * g) * Dv + dt2 * 32 + l31, Dv);
            a1 = __builtin_amdgcn_mfma_f32_32x32x16_bf16(wf, xf, a1, 0, 0, 0);
        }
        #pragma unroll
        for (int q = 0; q < 4; ++q) R1[dt2][q] = rpk(a1, q);
    }

    // register redistribution (R7-verified): haf[kt] = H1[row l31 of band][d = kt*16+8g+t]
    bf16x8 haf[4];
    #pragma unroll
    for (int kt = 0; kt < 4; ++kt) {
        const int dt2 = kt >> 1, qa = (2 * kt) & 3;
        plswap(R1[dt2][qa].x, R1[dt2][qa + 1].x);
        plswap(R1[dt2][qa].y, R1[dt2][qa + 1].y);
        haf[kt] = frag_from(R1[dt2][qa], R1[dt2][qa + 1]);
    }

    __syncthreads();   // barrier #2: every wave's Xs reads done -> Sb reusable

    // ===== L2 (normal): H2 = relu(H1 @ W2 + b2); H2T into Sb, one nt half at a time =====
    #pragma unroll
    for (int nt = 0; nt < 2; ++nt) {
        const float bb = b2[nt * 32 + l31];
        f32x16 a2;
        #pragma unroll
        for (int e = 0; e < 16; ++e) a2[e] = bb;
        #pragma unroll
        for (int kt = 0; kt < 4; ++kt) {
            const bf16x8 wf = PRE
                ? *(const bf16x8*)(wpk + (size_t)(8 + nt * 4 + kt) * 512 + l * 8)
                : frag_strided(W2 + (kt * 16 + 8 * g) * Dv + nt * 32 + l31, Dv);
            a2 = __builtin_amdgcn_mfma_f32_32x32x16_bf16(haf[kt], wf, a2, 0, 0, 0);
        }
        const int d2 = nt * 32 + l31;
        #pragma unroll
        for (int q = 0; q < 4; ++q) {   // k = 32w + 8q + 4g + 0..3 -> 8 B write
            const int inrow = 2 * (32 * w + 8 * q + 4 * g);
            const int addr  = d2 * 256 + (((inrow & ~15) ^ ((d2 & 7) << 4)) | (inrow & 15));
            *(uint2*)&Sb[addr] = rpk(a2, q);
        }
    }

    __syncthreads();   // barrier #3: H2T complete (read cross-wave below)

    // ===== P2 (swapped): outT-tile = H2T @ A_b ; wave w owns j-tile jt = w =====
    const float msk = mask[bi * Nv + 32 * w + l31] ? 1.0f : 0.0f;
    float* orow = out + (bi * Nv + 32 * w + l31) * Dv + 4 * g;
    const unsigned short* Apb = PRE ? apk + (size_t)b * 32 * 512 : nullptr;
    const float* Ab = A + (size_t)b * Nv * Nv;

    #pragma unroll
    for (int dts = 0; dts < 2; ++dts) {   // one d-half at a time (16-reg acc)
        const int d = dts * 32 + l31;
        f32x16 ao;
        #pragma unroll
        for (int e = 0; e < 16; ++e) ao[e] = 0.0f;
        #pragma unroll
        for (int kts = 0; kts < 8; ++kts) {
            const int inrow = kts * 32 + 16 * g;
            const bf16x8 hf = *(const bf16x8*)&Sb[d * 256 +
                (((inrow & ~15) ^ ((d & 7) << 4)) | (inrow & 15))];
            bf16x8 bfr;
            if (PRE) {
                bfr = *(const bf16x8*)(Apb + (size_t)(w * 8 + kts) * 512 + l * 8);
            } else {
                const float4* ap = (const float4*)(Ab + ((size_t)w * 32 + l31) * Nv
                                                     + kts * 16 + 8 * g);
                bfr = pack8f(ap[0], ap[1]);
            }
            ao = __builtin_amdgcn_mfma_f32_32x32x16_bf16(hf, bfr, ao, 0, 0, 0);
        }
        #pragma unroll
        for (int q = 0; q < 4; ++q)
            *(float4*)&orow[dts * 32 + q * 8] = make_float4(
                ao[4*q+0] * msk, ao[4*q+1] * msk, ao[4*q+2] * msk, ao[4*q+3] * msk);
    }
}

extern "C" void kernel_launch(void* const* d_in, const int* in_sizes, int n_in,
                              void* d_out, int out_size, void* d_ws, size_t ws_size,
                              hipStream_t stream) {
    const float* X    = (const float*)d_in[0];
    const float* A    = (const float*)d_in[1];
    const int*   mask = (const int*)d_in[2];
    const float* W1   = (const float*)d_in[3];
    const float* b1   = (const float*)d_in[4];
    const float* W2   = (const float*)d_in[5];
    const float* b2   = (const float*)d_in[6];
    float* out = (float*)d_out;

    dim3 grid(Nv, Bv);   // blocks sharing b adjacent -> A[b]/apk[b] L2-hot

    if (ws_size >= (size_t)WS_NEED) {
        unsigned short* wpk = (unsigned short*)d_ws;
        unsigned short* apk = (unsigned short*)((unsigned char*)d_ws + APK_OFF_B);
        pack_w32<<<4, 256, 0, stream>>>(W1, W2, wpk);
        pack_a32<<<512, 256, 0, stream>>>(A, apk);
        nested_conv_hyb<true><<<grid, 256, 0, stream>>>(
            X, A, mask, W1, b1, W2, b2, wpk, apk, out);
    } else {
        nested_conv_hyb<false><<<grid, 256, 0, stream>>>(
            X, A, mask, W1, b1, W2, b2, nullptr, nullptr, out);
    }
}